// Round 1
// baseline (458.972 us; speedup 1.0000x reference)
//
#include <hip/hip_runtime.h>

// GATv2 2-layer GNN, MI355X. Inputs/out fp32 (proven r3); compute bf16.
// Round-11: k_agg rework. (1) unified CPL template: layer1 CPL=16 (quarter
// owns 1 edge, head-split at lane 8 -> 3-stage reduce, 4 edges in flight),
// layer2 CPL=8 (4-stage reduce); (2) shuffle-reduce -> DPP v_add chains
// (VALU pipe, no lgkm waits in hot loop); (3) 2-deep software pipeline:
// prefetch ssrc[j+8] + xl rows[j+4] during compute of j. Rest unchanged.

#define DIN 128
#define F1 256   // H*DH layer 1
#define F2 128   // DOUT
#define NEG_SLOPE 0.2f

typedef unsigned short u16;
typedef __attribute__((ext_vector_type(8))) short short8;
typedef __attribute__((ext_vector_type(4))) float floatx4;

__device__ __forceinline__ float bf2f(u16 u) {
  return __uint_as_float(((unsigned int)u) << 16);
}
__device__ __forceinline__ u16 f2bf(float f) {   // round-to-nearest-even
  unsigned int x = __float_as_uint(f);
  return (u16)((x + 0x7fffu + ((x >> 16) & 1u)) >> 16);
}
__device__ __forceinline__ void load8(const u16* p, float (&f)[8]) {
  short8 v = *(const short8*)p;
#pragma unroll
  for (int k = 0; k < 8; k++) f[k] = bf2f((u16)v[k]);
}
__device__ __forceinline__ void load8p(const u16* p, float* f) {
  short8 v = *(const short8*)p;
#pragma unroll
  for (int k = 0; k < 8; k++) f[k] = bf2f((u16)v[k]);
}

// DPP-based add of lane (self ^ pattern); VALU pipe only.
// 0xB1 = quad_perm [1,0,3,2] (xor1), 0x4E = quad_perm [2,3,0,1] (xor2),
// 0x141 = row_half_mirror (crosses quads within 8), 0x140 = row_mirror
// (crosses 8-groups within 16). Valid reduce because prior stages make
// groups uniform before a mirror stage.
template <int CTRL>
__device__ __forceinline__ float dppadd(float s) {
  int t = __builtin_amdgcn_update_dpp(0, __float_as_int(s), CTRL, 0xF, 0xF, false);
  return s + __int_as_float(t);
}

// ---------------- fused convert + transpose + zero + self-detect ----------------
struct PTab { const void* src[8]; int off[9]; };
__global__ __launch_bounds__(256) void k_convert_all(
    const void* __restrict__ xsrc, u16* __restrict__ xb, int n4, int nxb,
    PTab t, u16* __restrict__ pb, int ptotal, int npb,
    const void* __restrict__ Wl1s, const void* __restrict__ Wr1s,
    const void* __restrict__ Wl2s, const void* __restrict__ Wr2s,
    u16* __restrict__ Wl1t, u16* __restrict__ Wr1t,
    u16* __restrict__ Wl2t, u16* __restrict__ Wr2t,
    int* __restrict__ zbase, int zn, int* __restrict__ flag) {
  __shared__ int flagS;
  int tid = threadIdx.x;
  if (tid < 64) {
    int cnt = 0;
#pragma unroll
    for (int i = 0; i < 2; ++i) {
      u16 v = ((const u16*)xsrc)[2 * (tid + 64 * i)];  // even u16: fp32 low halves
      int e = (v >> 7) & 0xFF;
      if (e >= 115 && e <= 130) cnt++;                 // bf16 N(0,1) exponent range
    }
#pragma unroll
    for (int m = 1; m <= 32; m <<= 1) cnt += __shfl_xor(cnt, m, 64);
    if (tid == 0) flagS = (cnt < 64) ? 1 : 0;
  }
  __syncthreads();
  const int fl = flagS;
  if (blockIdx.x == 0 && tid == 0) *flag = fl;   // persist for poolfinal

  int b = blockIdx.x;
  if (b < nxb) {                                  // x convert, 4 elems/thread
    int i = b * 256 + tid;
    if (i >= n4) return;
    if (fl) {
      float4 a = ((const float4*)xsrc)[i];
      ushort4 o;
      o.x = f2bf(a.x); o.y = f2bf(a.y); o.z = f2bf(a.z); o.w = f2bf(a.w);
      ((ushort4*)xb)[i] = o;
    } else {
      ((ulong1*)xb)[i] = ((const ulong1*)xsrc)[i];
    }
    return;
  }
  b -= nxb;
  if (b < npb) {                                  // small params (no W's)
    int i = b * 256 + tid;
    if (i >= ptotal) return;
    int s = 0;
#pragma unroll
    for (int k = 1; k < 8; k++) s += (i >= t.off[k]);
    int local = i - t.off[s];
    pb[i] = fl ? f2bf(((const float*)t.src[s])[local]) : ((const u16*)t.src[s])[local];
    return;
  }
  b -= npb;
  if (b < 512) {
    // weight transposes: W[K,NL] -> Wt[NL,K]; 4 segs x 128 blocks
    int seg = b >> 7;
    int i = (b & 127) * 256 + tid;
    const void* s; u16* d; int NL, sh;
    if      (seg == 0) { s = Wl1s; d = Wl1t; NL = 256; sh = 7; }
    else if (seg == 1) { s = Wr1s; d = Wr1t; NL = 256; sh = 7; }
    else if (seg == 2) { s = Wl2s; d = Wl2t; NL = 128; sh = 8; }
    else               { s = Wr2s; d = Wr2t; NL = 128; sh = 8; }
    int n = i >> sh, k = i & ((1 << sh) - 1);
    int si = k * NL + n;
    d[i] = fl ? f2bf(((const float*)s)[si]) : ((const u16*)s)[si];
    return;
  }
  b -= 512;
  int i = b * 256 + tid;                          // zero region (ints)
  if (i < zn) zbase[i] = 0;
}

// ---------------- CSR build ----------------
__global__ void k_hist(const int* __restrict__ ei, int* __restrict__ hist,
                       int E, int Etot) {
  int e = blockIdx.x * 256 + threadIdx.x;
  if (e >= Etot) return;
  int dst = (e < E) ? ei[E + e] : (e - E);
  atomicAdd(&hist[dst], 1);
}

// single-pass decoupled-lookback exclusive scan; writes rowptr & cursor
__global__ void k_scan(const int* __restrict__ hist, int* __restrict__ rowptr,
                       int* __restrict__ cursor, unsigned long long* __restrict__ pstate,
                       int* __restrict__ ctr, int n, int Etot) {
  __shared__ int tmp[256];
  __shared__ int bidS, offS;
  int t = threadIdx.x;
  if (t == 0) bidS = atomicAdd(ctr, 1);
  __syncthreads();
  int bid = bidS;
  int gid = bid * 256 + t;
  int v = (gid < n) ? hist[gid] : 0;
  tmp[t] = v;
  __syncthreads();
  for (int off = 1; off < 256; off <<= 1) {
    int add = (t >= off) ? tmp[t - off] : 0;
    __syncthreads();
    tmp[t] += add;
    __syncthreads();
  }
  if (t == 0) {
    int total = tmp[255];
    unsigned long long st =
        ((unsigned long long)(bid == 0 ? 2 : 1) << 32) | (unsigned)total;
    atomicExch(&pstate[bid], st);
    int off = 0;
    if (bid > 0) {
      int b = bid - 1;
      while (true) {
        unsigned long long s;
        do { s = atomicAdd(&pstate[b], 0ULL); } while ((s >> 32) == 0);
        off += (int)(unsigned)s;
        if ((s >> 32) == 2) break;
        b--;
      }
      atomicExch(&pstate[bid],
                 ((unsigned long long)2 << 32) | (unsigned)(off + total));
    }
    offS = off;
  }
  __syncthreads();
  int off = offS;
  if (gid < n) {
    int ex = off + tmp[t] - v;
    rowptr[gid] = ex;
    cursor[gid] = ex;
  }
  if (gid == 0) rowptr[n] = Etot;
}

__global__ void k_scatter(const int* __restrict__ ei, int* __restrict__ cursor,
                          int* __restrict__ ssrc, int E, int Etot) {
  int e = blockIdx.x * 256 + threadIdx.x;
  if (e >= Etot) return;
  int src, dst;
  if (e < E) { src = ei[e]; dst = ei[E + e]; }
  else       { src = e - E; dst = e - E; }
  int pos = atomicAdd(&cursor[dst], 1);
  ssrc[pos] = src;
}

// ---------------- GEMM: LDS-free, B pre-transposed Bt[NL][K] (r9-proven) ----------------
template<int K, bool RB>
__global__ __launch_bounds__(256) void k_gemm(
    const u16* __restrict__ A, const u16* __restrict__ Blt, const u16* __restrict__ Brt,
    int NL, u16* __restrict__ Cl, u16* __restrict__ Cr, int M,
    const float* __restrict__ rbias) {
  const int tid = threadIdx.x;
  const int m0 = blockIdx.x * 64;
  const int n0g = blockIdx.y * 64;
  const u16* Bt; u16* C; int col0;
  if (n0g < NL) { Bt = Blt; C = Cl; col0 = n0g; }
  else          { Bt = Brt; C = Cr; col0 = n0g - NL; }

  const int wave = tid >> 6, lane = tid & 63;
  const int wm = wave >> 1, wn = wave & 1;
  const int quad = lane >> 4, l16 = lane & 15;

  floatx4 acc[2][2] = {};
#pragma unroll
  for (int k0 = 0; k0 < K; k0 += 32) {
    short8 af[2], bfr[2];
#pragma unroll
    for (int mt = 0; mt < 2; mt++) {
      int row = m0 + wm * 32 + mt * 16 + l16;
      if (row > M - 1) row = M - 1;
      af[mt] = *(const short8*)(A + (size_t)row * K + k0 + quad * 8);
    }
#pragma unroll
    for (int nt = 0; nt < 2; nt++) {
      int nn = col0 + wn * 32 + nt * 16 + l16;
      bfr[nt] = *(const short8*)(Bt + (size_t)nn * K + k0 + quad * 8);
    }
#pragma unroll
    for (int mt = 0; mt < 2; mt++)
#pragma unroll
      for (int nt = 0; nt < 2; nt++)
        acc[mt][nt] = __builtin_amdgcn_mfma_f32_16x16x32_bf16(af[mt], bfr[nt], acc[mt][nt], 0, 0, 0);
  }

#pragma unroll
  for (int mt = 0; mt < 2; mt++)
#pragma unroll
    for (int nt = 0; nt < 2; nt++) {
      float rb = 0.f;
      if (RB) rb = rbias[n0g + wn * 32 + nt * 16 + l16];
#pragma unroll
      for (int r = 0; r < 4; r++) {
        int row = m0 + wm * 32 + mt * 16 + quad * 4 + r;
        if (row < M) {
          int col = col0 + wn * 32 + nt * 16 + l16;
          C[(size_t)row * NL + col] = f2bf(acc[mt][nt][r] + rb);
        }
      }
    }
}

// ---------------- aggregation: quarter-per-edge, DPP reduce, 2-deep pipeline ----------------
// CPL = channels per lane (F = 16*CPL). CPL=16: layer 1 (2 heads, head
// boundary at lane 8 -> 3-stage score reduce). CPL=8: layer 2 (1 head,
// 4-stage reduce). Each 16-lane quarter owns one edge -> 4 edges in
// flight per wave; next edge's row is prefetched during current compute.
template<int CPL, int MODE>
__global__ __launch_bounds__(256) void k_agg(
    const u16* __restrict__ xl, const u16* __restrict__ xr,
    const u16* __restrict__ att, const u16* __restrict__ bias,
    const int* __restrict__ rowptr, const int* __restrict__ ssrc,
    void* __restrict__ outv, int n) {
  constexpr int F = CPL * 16;
  constexpr int NV = CPL / 8;   // short8 vectors per lane
  int wave = threadIdx.x >> 6, lane = threadIdx.x & 63;
  int node = blockIdx.x * 4 + wave;
  if (node >= n) return;
  const int q = lane >> 4, l = lane & 15;
  const int ch0 = l * CPL;

  float xrv[CPL], attv[CPL], acc[CPL];
#pragma unroll
  for (int v = 0; v < NV; v++) {
    load8p(xr + (size_t)node * F + ch0 + v * 8, &xrv[v * 8]);
    load8p(att + ch0 + v * 8, &attv[v * 8]);
  }
#pragma unroll
  for (int c = 0; c < CPL; c++) acc[c] = 0.f;

  const int jb = rowptr[node], je = rowptr[node + 1];
  float l_run = 0.f;

  // software pipeline: cur = row for edge jb+q; snxt = src idx for jb+4+q
  int jj = jb + q;
  int scur = ssrc[jj < je ? jj : je - 1];
  int jn = jb + 4 + q;
  int snxt = ssrc[jn < je ? jn : je - 1];
  short8 cur[NV], nxt[NV];
#pragma unroll
  for (int v = 0; v < NV; v++)
    cur[v] = *(const short8*)(xl + (size_t)scur * F + ch0 + v * 8);

  for (int j = jb; j < je; j += 4) {
    // prefetch next edge's row + next-next src index
#pragma unroll
    for (int v = 0; v < NV; v++)
      nxt[v] = *(const short8*)(xl + (size_t)snxt * F + ch0 + v * 8);
    int jnn = j + 8 + q;
    snxt = ssrc[jnn < je ? jnn : je - 1];

    float xlv[CPL];
#pragma unroll
    for (int v = 0; v < NV; v++)
#pragma unroll
      for (int k = 0; k < 8; k++) xlv[v * 8 + k] = bf2f((u16)cur[v][k]);

    float s = 0.f;
#pragma unroll
    for (int c = 0; c < CPL; c++) {
      float m = xlv[c] + xrv[c];
      m = m > 0.f ? m : NEG_SLOPE * m;
      s += m * attv[c];
    }
    // score reduce on the VALU pipe (DPP), no LDS-pipe waits:
    s = dppadd<0xB1>(s);        // xor 1 (quad_perm)
    s = dppadd<0x4E>(s);        // xor 2 (quad_perm)
    s = dppadd<0x141>(s);       // cross-quad within 8 (row_half_mirror)
    if (CPL == 8) s = dppadd<0x140>(s);  // cross-8 within 16 (row_mirror)
    // CPL==16: lanes 0-7 hold head-0 score, lanes 8-15 head-1 score.

    float p = (j + q < je) ? __expf(fminf(s, 80.f)) : 0.f;
    l_run += p;
#pragma unroll
    for (int c = 0; c < CPL; c++) acc[c] += p * xlv[c];

#pragma unroll
    for (int v = 0; v < NV; v++) cur[v] = nxt[v];
  }

  // combine the 4 edge slots (once per node)
#pragma unroll
  for (int c = 0; c < CPL; c++) {
    acc[c] += __shfl_xor(acc[c], 16, 64);
    acc[c] += __shfl_xor(acc[c], 32, 64);
  }
  l_run += __shfl_xor(l_run, 16, 64);
  l_run += __shfl_xor(l_run, 32, 64);

  if (q == 0) {
    float inv = 1.f / (l_run + 1e-16f);
    if (MODE == 0) {
#pragma unroll
      for (int v = 0; v < NV; v++) {
        short8 o;
#pragma unroll
        for (int k = 0; k < 8; k++) {
          float t = acc[v * 8 + k] * inv + bf2f(bias[ch0 + v * 8 + k]);
          t = t > 0.f ? t : (__expf(t) - 1.f);        // elu
          o[k] = (short)f2bf(t);
        }
        *(short8*)((u16*)outv + (size_t)node * F + ch0 + v * 8) = o;
      }
    } else {
#pragma unroll
      for (int v = 0; v < NV; v++) {
        float w[8];
#pragma unroll
        for (int k = 0; k < 8; k++)
          w[k] = acc[v * 8 + k] * inv + bf2f(bias[ch0 + v * 8 + k]);
        float* op = (float*)outv + (size_t)node * F + ch0 + v * 8;
        *(float4*)op = make_float4(w[0], w[1], w[2], w[3]);
        *(float4*)(op + 4) = make_float4(w[4], w[5], w[6], w[7]);
      }
    }
  }
}

// ---------------- BN stats (vectorized) + fold into transposed gemm2 weights ----------------
// block: 8 row-lanes x 32 ch-lanes; thread accumulates 8 channels via short8.
__global__ __launch_bounds__(256) void k_stats(
    const u16* __restrict__ h, float* __restrict__ gsum,
    float* __restrict__ gsumsq, int n) {
  __shared__ float smS[8][256], smQ[8][256];
  int t = threadIdx.x;
  int rg = t >> 5, cl = t & 31;
  int ch0 = cl * 8;
  float s[8] = {}, q[8] = {};
  for (int r = blockIdx.x * 8 + rg; r < n; r += gridDim.x * 8) {
    float v[8];
    load8(h + (size_t)r * F1 + ch0, v);
#pragma unroll
    for (int k = 0; k < 8; k++) { s[k] += v[k]; q[k] += v[k] * v[k]; }
  }
#pragma unroll
  for (int k = 0; k < 8; k++) { smS[rg][ch0 + k] = s[k]; smQ[rg][ch0 + k] = q[k]; }
  __syncthreads();
  float ts = 0.f, tq = 0.f;
#pragma unroll
  for (int g = 0; g < 8; g++) { ts += smS[g][t]; tq += smQ[g][t]; }
  atomicAdd(&gsum[t], ts);
  atomicAdd(&gsumsq[t], tq);
}

__global__ __launch_bounds__(256) void k_foldbn(
    const float* __restrict__ gsum, const float* __restrict__ gsumsq,
    const u16* __restrict__ gamma, const u16* __restrict__ beta,
    u16* __restrict__ Wl2t, u16* __restrict__ Wr2t,
    float* __restrict__ rbias, float invn) {
  __shared__ float red[8];
  int t = threadIdx.x, n = blockIdx.x;   // 128 blocks x 256 threads
  float mu = gsum[t] * invn;
  float var = gsumsq[t] * invn - mu * mu;
  float a = bf2f(gamma[t]) * rsqrtf(fmaxf(var, 0.f) + 1e-5f);
  float b = bf2f(beta[t]) - mu * a;
  float wl = bf2f(Wl2t[n * 256 + t]);
  float wr = bf2f(Wr2t[n * 256 + t]);
  float sl = b * wl, sr = b * wr;
  Wl2t[n * 256 + t] = f2bf(a * wl);
  Wr2t[n * 256 + t] = f2bf(a * wr);
#pragma unroll
  for (int m = 1; m <= 32; m <<= 1) {
    sl += __shfl_xor(sl, m, 64);
    sr += __shfl_xor(sr, m, 64);
  }
  int wave = t >> 6, lane = t & 63;
  if (lane == 0) { red[wave] = sl; red[4 + wave] = sr; }
  __syncthreads();
  if (t == 0) rbias[n] = red[0] + red[1] + red[2] + red[3];
  if (t == 1) rbias[128 + n] = red[4] + red[5] + red[6] + red[7];
}

// ---------------- pool + final linear: 1 block/graph, binary-search bounds ----------------
__device__ __forceinline__ int lowerb(const int* __restrict__ a, int n, int key) {
  int lo = 0, hi = n;
  while (lo < hi) { int m = (lo + hi) >> 1; if (a[m] < key) lo = m + 1; else hi = m; }
  return lo;
}

__global__ __launch_bounds__(256) void k_poolfinal(
    const float* __restrict__ h2, const int* __restrict__ batch,
    const u16* __restrict__ Wlin, const u16* __restrict__ blin,
    void* __restrict__ out, const int* __restrict__ flag, int G, int N) {
  __shared__ float sm[4][128];
  int g = blockIdx.x;
  int wave = threadIdx.x >> 6, lane = threadIdx.x & 63;
  int jb = lowerb(batch, N, g);
  int je = lowerb(batch, N, g + 1);
  int ch = lane * 2;
  float c0 = 0.f, c1 = 0.f;
  for (int r = jb + wave; r < je; r += 4) {
    float2 v = *(const float2*)(h2 + (size_t)r * F2 + ch);
    c0 += v.x; c1 += v.y;
  }
  sm[wave][ch] = c0;
  sm[wave][ch + 1] = c1;
  __syncthreads();
  if (wave == 0) {
    c0 = sm[0][ch] + sm[1][ch] + sm[2][ch] + sm[3][ch];
    c1 = sm[0][ch + 1] + sm[1][ch + 1] + sm[2][ch + 1] + sm[3][ch + 1];
    float cf = fmaxf((float)(je - jb), 1.f);
    c0 /= cf; c1 /= cf;
    float s0 = c0 * bf2f(Wlin[ch * 2 + 0]) + c1 * bf2f(Wlin[(ch + 1) * 2 + 0]);
    float s1 = c0 * bf2f(Wlin[ch * 2 + 1]) + c1 * bf2f(Wlin[(ch + 1) * 2 + 1]);
#pragma unroll
    for (int m = 1; m <= 32; m <<= 1) {
      s0 += __shfl_xor(s0, m, 64);
      s1 += __shfl_xor(s1, m, 64);
    }
    if (lane == 0) {
      float o0 = s0 + bf2f(blin[0]);
      float o1 = s1 + bf2f(blin[1]);
      if (*flag) {
        ((float*)out)[g * 2 + 0] = o0;
        ((float*)out)[g * 2 + 1] = o1;
      } else {
        ((u16*)out)[g * 2 + 0] = f2bf(o0);
        ((u16*)out)[g * 2 + 1] = f2bf(o1);
      }
    }
  }
}

// ---------------- host ----------------
extern "C" void kernel_launch(void* const* d_in, const int* in_sizes, int n_in,
                              void* d_out, int out_size, void* d_ws, size_t ws_size,
                              hipStream_t stream) {
  const int* ei    = (const int*)d_in[1];
  const int* batch = (const int*)d_in[2];

  const int N = in_sizes[0] / DIN;
  const int E = in_sizes[1] / 2;
  const int G = out_size / 2;
  const int Etot = E + N;

  char* p = (char*)d_ws;
  auto alloc = [&](size_t bytes) {
    char* r = p;
    p += (bytes + 255) & ~(size_t)255;
    return r;
  };
  int*  flag     = (int*)alloc(256);
  // ---- zero region (zeroed by convert_all): hist | gsum | gsumsq | pstate | ctr ----
  int*  hist     = (int*)alloc((size_t)N * 4);
  float* gsum    = (float*)alloc(1024);
  float* gsumsq  = (float*)alloc(1024);
  unsigned long long* pstate = (unsigned long long*)alloc(2048);
  int*  ctr      = (int*)alloc(256);
  int   zn       = (int)(((char*)ctr + 256) - (char*)hist) / 4;
  // ---- rest ----
  int*  rowptr   = (int*)alloc((size_t)(N + 1) * 4);
  int*  cursor   = (int*)alloc((size_t)N * 4);
  float* rbias   = (float*)alloc(256 * 4);
  int*  ssrc     = (int*)alloc((size_t)Etot * 4);
  u16*  xb       = (u16*)alloc((size_t)N * DIN * 2);
  u16*  pb       = (u16*)alloc(4096);
  u16*  Wl1t     = (u16*)alloc(DIN * F1 * 2);   // [256][128]
  u16*  Wr1t     = (u16*)alloc(DIN * F1 * 2);
  u16*  Wl2t     = (u16*)alloc(F1 * F2 * 2);    // [128][256]
  u16*  Wr2t     = (u16*)alloc(F1 * F2 * 2);
  u16*  regionA  = (u16*)alloc((size_t)N * F1 * 2);
  u16*  regionB  = (u16*)alloc((size_t)N * F1 * 2);
  u16*  regionC  = (u16*)alloc((size_t)N * F1 * 2);

  u16*  xl1  = regionA;
  u16*  xr1  = regionB;
  u16*  helu = regionC;                 // bf16 [N,F1] (gemm2 reads directly)
  u16*  xl2  = regionB;                 // bf16 [N,F2]  (B free after agg1)
  u16*  xr2  = regionB + (size_t)N * F2;
  float* h2  = (float*)regionA;         // fp32 [N,F2]  (A free after gemm2)

  // ---- fused convert (+transpose, +zero, +self-detect) ----
  const int pidx[8] = {5, 6, 7, 8, 11, 12, 13, 14};  // att1,b1,gamma,beta,att2,b2,Wlin,blin
  PTab tab;
  int accum = 0;
  for (int i = 0; i < 8; i++) {
    tab.src[i] = d_in[pidx[i]];
    tab.off[i] = accum;
    accum += in_sizes[pidx[i]];
  }
  tab.off[8] = accum;
  int n4 = in_sizes[0] / 4;
  int nxb = (n4 + 255) / 256;
  int npb = (accum + 255) / 256;
  int nzb = (zn + 255) / 256;
  k_convert_all<<<nxb + npb + 512 + nzb, 256, 0, stream>>>(
      d_in[0], xb, n4, nxb, tab, pb, accum, npb,
      d_in[3], d_in[4], d_in[9], d_in[10], Wl1t, Wr1t, Wl2t, Wr2t,
      hist, zn, flag);
  u16 *pAtt1 = pb + tab.off[0], *pB1 = pb + tab.off[1], *pGamma = pb + tab.off[2],
      *pBeta = pb + tab.off[3], *pAtt2 = pb + tab.off[4], *pB2 = pb + tab.off[5],
      *pWlin = pb + tab.off[6], *pBlin = pb + tab.off[7];

  const int eb = (Etot + 255) / 256;
  const int sb = (N + 255) / 256;

  k_hist<<<eb, 256, 0, stream>>>(ei, hist, E, Etot);
  k_scan<<<sb, 256, 0, stream>>>(hist, rowptr, cursor, pstate, ctr, N, Etot);
  k_scatter<<<eb, 256, 0, stream>>>(ei, cursor, ssrc, E, Etot);

  dim3 g1((N + 63) / 64, (2 * F1) / 64);
  k_gemm<DIN, false><<<g1, 256, 0, stream>>>(xb, Wl1t, Wr1t, F1, xl1, xr1, N, nullptr);

  k_agg<16, 0><<<(N + 3) / 4, 256, 0, stream>>>(xl1, xr1, pAtt1, pB1, rowptr, ssrc, helu, N);

  k_stats<<<256, 256, 0, stream>>>(helu, gsum, gsumsq, N);
  k_foldbn<<<128, 256, 0, stream>>>(gsum, gsumsq, pGamma, pBeta, Wl2t, Wr2t, rbias,
                                    1.0f / (float)N);

  dim3 g2((N + 63) / 64, (2 * F2) / 64);
  k_gemm<F1, true><<<g2, 256, 0, stream>>>(helu, Wl2t, Wr2t, F2, xl2, xr2, N, rbias);

  k_agg<8, 1><<<(N + 3) / 4, 256, 0, stream>>>(xl2, xr2, pAtt2, pB2, rowptr, ssrc, h2, N);

  k_poolfinal<<<G, 256, 0, stream>>>(h2, batch, pWlin, pBlin, d_out, flag, G, N);
}

// Round 2
// 448.641 us; speedup vs baseline: 1.0230x; 1.0230x over previous
//
#include <hip/hip_runtime.h>

// GATv2 2-layer GNN, MI355X. Inputs/out fp32 (proven r3); compute bf16.
// Round-12: packed-FP32 k_agg. r11 made agg VALU-issue-bound (VALUBusy 83%,
// ~116 wave-instr / 4-edge slot matches 88us). This round cuts issue count:
// (1) VOP3P packed f32 via inline asm (v_pk_add/fma_f32) -> 2 ch/instr;
// (2) leaky(m) = 0.6m + 0.4|m| folded into att: s += (0.6att)*m + (0.4att)*|m|
//     (no v_pk_max_f32 exists; abs = v_and per half);
// (3) jb/je -> SGPR via readfirstlane (loop bookkeeping on scalar pipe).
// Per-channel VALU 6 -> 4. Rest of pipeline unchanged (r9-r11 proven).

#define DIN 128
#define F1 256   // H*DH layer 1
#define F2 128   // DOUT
#define NEG_SLOPE 0.2f

typedef unsigned short u16;
typedef __attribute__((ext_vector_type(8))) short short8;
typedef __attribute__((ext_vector_type(4))) float floatx4;
typedef __attribute__((ext_vector_type(2))) float f32x2;

__device__ __forceinline__ float bf2f(u16 u) {
  return __uint_as_float(((unsigned int)u) << 16);
}
__device__ __forceinline__ u16 f2bf(float f) {   // round-to-nearest-even
  unsigned int x = __float_as_uint(f);
  return (u16)((x + 0x7fffu + ((x >> 16) & 1u)) >> 16);
}
__device__ __forceinline__ void load8(const u16* p, float (&f)[8]) {
  short8 v = *(const short8*)p;
#pragma unroll
  for (int k = 0; k < 8; k++) f[k] = bf2f((u16)v[k]);
}

// expand one dword holding 2 bf16 (little-endian: lo ch = low u16)
__device__ __forceinline__ f32x2 bf2x(unsigned int u) {
  f32x2 r;
  r.x = __uint_as_float(u << 16);
  r.y = __uint_as_float(u & 0xffff0000u);
  return r;
}
// packed fp32 (VOP3P, full-rate on CDNA): 2 f32 lanes per instruction
__device__ __forceinline__ f32x2 pk_add(f32x2 a, f32x2 b) {
  f32x2 d;
  asm("v_pk_add_f32 %0, %1, %2" : "=v"(d) : "v"(a), "v"(b));
  return d;
}
__device__ __forceinline__ f32x2 pk_fma(f32x2 a, f32x2 b, f32x2 c) {
  f32x2 d;
  asm("v_pk_fma_f32 %0, %1, %2, %3" : "=v"(d) : "v"(a), "v"(b), "v"(c));
  return d;
}
__device__ __forceinline__ f32x2 pk_abs(f32x2 a) {
  f32x2 r;
  r.x = __uint_as_float(__float_as_uint(a.x) & 0x7fffffffu);
  r.y = __uint_as_float(__float_as_uint(a.y) & 0x7fffffffu);
  return r;
}

// DPP-based add of lane (self ^ pattern); VALU pipe only.
// 0xB1 = quad_perm xor1, 0x4E = quad_perm xor2, 0x141 = row_half_mirror
// (crosses quads within 8), 0x140 = row_mirror (crosses 8-groups within 16).
template <int CTRL>
__device__ __forceinline__ float dppadd(float s) {
  int t = __builtin_amdgcn_update_dpp(0, __float_as_int(s), CTRL, 0xF, 0xF, false);
  return s + __int_as_float(t);
}

// ---------------- fused convert + transpose + zero + self-detect ----------------
struct PTab { const void* src[8]; int off[9]; };
__global__ __launch_bounds__(256) void k_convert_all(
    const void* __restrict__ xsrc, u16* __restrict__ xb, int n4, int nxb,
    PTab t, u16* __restrict__ pb, int ptotal, int npb,
    const void* __restrict__ Wl1s, const void* __restrict__ Wr1s,
    const void* __restrict__ Wl2s, const void* __restrict__ Wr2s,
    u16* __restrict__ Wl1t, u16* __restrict__ Wr1t,
    u16* __restrict__ Wl2t, u16* __restrict__ Wr2t,
    int* __restrict__ zbase, int zn, int* __restrict__ flag) {
  __shared__ int flagS;
  int tid = threadIdx.x;
  if (tid < 64) {
    int cnt = 0;
#pragma unroll
    for (int i = 0; i < 2; ++i) {
      u16 v = ((const u16*)xsrc)[2 * (tid + 64 * i)];  // even u16: fp32 low halves
      int e = (v >> 7) & 0xFF;
      if (e >= 115 && e <= 130) cnt++;                 // bf16 N(0,1) exponent range
    }
#pragma unroll
    for (int m = 1; m <= 32; m <<= 1) cnt += __shfl_xor(cnt, m, 64);
    if (tid == 0) flagS = (cnt < 64) ? 1 : 0;
  }
  __syncthreads();
  const int fl = flagS;
  if (blockIdx.x == 0 && tid == 0) *flag = fl;   // persist for poolfinal

  int b = blockIdx.x;
  if (b < nxb) {                                  // x convert, 4 elems/thread
    int i = b * 256 + tid;
    if (i >= n4) return;
    if (fl) {
      float4 a = ((const float4*)xsrc)[i];
      ushort4 o;
      o.x = f2bf(a.x); o.y = f2bf(a.y); o.z = f2bf(a.z); o.w = f2bf(a.w);
      ((ushort4*)xb)[i] = o;
    } else {
      ((ulong1*)xb)[i] = ((const ulong1*)xsrc)[i];
    }
    return;
  }
  b -= nxb;
  if (b < npb) {                                  // small params (no W's)
    int i = b * 256 + tid;
    if (i >= ptotal) return;
    int s = 0;
#pragma unroll
    for (int k = 1; k < 8; k++) s += (i >= t.off[k]);
    int local = i - t.off[s];
    pb[i] = fl ? f2bf(((const float*)t.src[s])[local]) : ((const u16*)t.src[s])[local];
    return;
  }
  b -= npb;
  if (b < 512) {
    // weight transposes: W[K,NL] -> Wt[NL,K]; 4 segs x 128 blocks
    int seg = b >> 7;
    int i = (b & 127) * 256 + tid;
    const void* s; u16* d; int NL, sh;
    if      (seg == 0) { s = Wl1s; d = Wl1t; NL = 256; sh = 7; }
    else if (seg == 1) { s = Wr1s; d = Wr1t; NL = 256; sh = 7; }
    else if (seg == 2) { s = Wl2s; d = Wl2t; NL = 128; sh = 8; }
    else               { s = Wr2s; d = Wr2t; NL = 128; sh = 8; }
    int n = i >> sh, k = i & ((1 << sh) - 1);
    int si = k * NL + n;
    d[i] = fl ? f2bf(((const float*)s)[si]) : ((const u16*)s)[si];
    return;
  }
  b -= 512;
  int i = b * 256 + tid;                          // zero region (ints)
  if (i < zn) zbase[i] = 0;
}

// ---------------- CSR build ----------------
__global__ void k_hist(const int* __restrict__ ei, int* __restrict__ hist,
                       int E, int Etot) {
  int e = blockIdx.x * 256 + threadIdx.x;
  if (e >= Etot) return;
  int dst = (e < E) ? ei[E + e] : (e - E);
  atomicAdd(&hist[dst], 1);
}

// single-pass decoupled-lookback exclusive scan; writes rowptr & cursor
__global__ void k_scan(const int* __restrict__ hist, int* __restrict__ rowptr,
                       int* __restrict__ cursor, unsigned long long* __restrict__ pstate,
                       int* __restrict__ ctr, int n, int Etot) {
  __shared__ int tmp[256];
  __shared__ int bidS, offS;
  int t = threadIdx.x;
  if (t == 0) bidS = atomicAdd(ctr, 1);
  __syncthreads();
  int bid = bidS;
  int gid = bid * 256 + t;
  int v = (gid < n) ? hist[gid] : 0;
  tmp[t] = v;
  __syncthreads();
  for (int off = 1; off < 256; off <<= 1) {
    int add = (t >= off) ? tmp[t - off] : 0;
    __syncthreads();
    tmp[t] += add;
    __syncthreads();
  }
  if (t == 0) {
    int total = tmp[255];
    unsigned long long st =
        ((unsigned long long)(bid == 0 ? 2 : 1) << 32) | (unsigned)total;
    atomicExch(&pstate[bid], st);
    int off = 0;
    if (bid > 0) {
      int b = bid - 1;
      while (true) {
        unsigned long long s;
        do { s = atomicAdd(&pstate[b], 0ULL); } while ((s >> 32) == 0);
        off += (int)(unsigned)s;
        if ((s >> 32) == 2) break;
        b--;
      }
      atomicExch(&pstate[bid],
                 ((unsigned long long)2 << 32) | (unsigned)(off + total));
    }
    offS = off;
  }
  __syncthreads();
  int off = offS;
  if (gid < n) {
    int ex = off + tmp[t] - v;
    rowptr[gid] = ex;
    cursor[gid] = ex;
  }
  if (gid == 0) rowptr[n] = Etot;
}

__global__ void k_scatter(const int* __restrict__ ei, int* __restrict__ cursor,
                          int* __restrict__ ssrc, int E, int Etot) {
  int e = blockIdx.x * 256 + threadIdx.x;
  if (e >= Etot) return;
  int src, dst;
  if (e < E) { src = ei[e]; dst = ei[E + e]; }
  else       { src = e - E; dst = e - E; }
  int pos = atomicAdd(&cursor[dst], 1);
  ssrc[pos] = src;
}

// ---------------- GEMM: LDS-free, B pre-transposed Bt[NL][K] (r9-proven) ----------------
template<int K, bool RB>
__global__ __launch_bounds__(256) void k_gemm(
    const u16* __restrict__ A, const u16* __restrict__ Blt, const u16* __restrict__ Brt,
    int NL, u16* __restrict__ Cl, u16* __restrict__ Cr, int M,
    const float* __restrict__ rbias) {
  const int tid = threadIdx.x;
  const int m0 = blockIdx.x * 64;
  const int n0g = blockIdx.y * 64;
  const u16* Bt; u16* C; int col0;
  if (n0g < NL) { Bt = Blt; C = Cl; col0 = n0g; }
  else          { Bt = Brt; C = Cr; col0 = n0g - NL; }

  const int wave = tid >> 6, lane = tid & 63;
  const int wm = wave >> 1, wn = wave & 1;
  const int quad = lane >> 4, l16 = lane & 15;

  floatx4 acc[2][2] = {};
#pragma unroll
  for (int k0 = 0; k0 < K; k0 += 32) {
    short8 af[2], bfr[2];
#pragma unroll
    for (int mt = 0; mt < 2; mt++) {
      int row = m0 + wm * 32 + mt * 16 + l16;
      if (row > M - 1) row = M - 1;
      af[mt] = *(const short8*)(A + (size_t)row * K + k0 + quad * 8);
    }
#pragma unroll
    for (int nt = 0; nt < 2; nt++) {
      int nn = col0 + wn * 32 + nt * 16 + l16;
      bfr[nt] = *(const short8*)(Bt + (size_t)nn * K + k0 + quad * 8);
    }
#pragma unroll
    for (int mt = 0; mt < 2; mt++)
#pragma unroll
      for (int nt = 0; nt < 2; nt++)
        acc[mt][nt] = __builtin_amdgcn_mfma_f32_16x16x32_bf16(af[mt], bfr[nt], acc[mt][nt], 0, 0, 0);
  }

#pragma unroll
  for (int mt = 0; mt < 2; mt++)
#pragma unroll
    for (int nt = 0; nt < 2; nt++) {
      float rb = 0.f;
      if (RB) rb = rbias[n0g + wn * 32 + nt * 16 + l16];
#pragma unroll
      for (int r = 0; r < 4; r++) {
        int row = m0 + wm * 32 + mt * 16 + quad * 4 + r;
        if (row < M) {
          int col = col0 + wn * 32 + nt * 16 + l16;
          C[(size_t)row * NL + col] = f2bf(acc[mt][nt][r] + rb);
        }
      }
    }
}

// ---------------- aggregation: quarter-per-edge, packed f32, DPP reduce ----------------
// CPL = channels per lane (F = 16*CPL). CPL=16: layer 1 (2 heads, head
// boundary at lane 8 -> 3-stage score reduce). CPL=8: layer 2 (1 head,
// 4-stage reduce). Each 16-lane quarter owns one edge; 2-deep pipeline.
// Score: s += (0.6 att)*m + (0.4 att)*|m|  ==  att * leakyrelu_{0.2}(m).
template<int CPL, int MODE>
__global__ __launch_bounds__(256) void k_agg(
    const u16* __restrict__ xl, const u16* __restrict__ xr,
    const u16* __restrict__ att, const u16* __restrict__ bias,
    const int* __restrict__ rowptr, const int* __restrict__ ssrc,
    void* __restrict__ outv, int n) {
  constexpr int F = CPL * 16;
  constexpr int NV = CPL / 8;   // uint4 (16B) loads per edge-lane
  constexpr int NP = CPL / 2;   // f32x2 pairs per lane
  int wave = threadIdx.x >> 6, lane = threadIdx.x & 63;
  int node = blockIdx.x * 4 + wave;
  if (node >= n) return;
  const int q = lane >> 4, l = lane & 15;
  const int ch0 = l * CPL;

  f32x2 xr2[NP], a06[NP], a04[NP], acc2[NP];
  {
    const unsigned int* xru = (const unsigned int*)(xr + (size_t)node * F + ch0);
    const unsigned int* atu = (const unsigned int*)(att + ch0);
#pragma unroll
    for (int p = 0; p < NP; p++) {
      xr2[p] = bf2x(xru[p]);
      f32x2 a = bf2x(atu[p]);
      a06[p].x = 0.6f * a.x; a06[p].y = 0.6f * a.y;
      a04[p].x = 0.4f * a.x; a04[p].y = 0.4f * a.y;
      acc2[p].x = 0.f;       acc2[p].y = 0.f;
    }
  }

  const int jb = __builtin_amdgcn_readfirstlane(rowptr[node]);
  const int je = __builtin_amdgcn_readfirstlane(rowptr[node + 1]);
  float l_run = 0.f;

  // software pipeline: cur = row for edge jb+q; snxt = src idx for jb+4+q
  int jj = jb + q;
  int scur = ssrc[jj < je ? jj : je - 1];
  int jn = jb + 4 + q;
  int snxt = ssrc[jn < je ? jn : je - 1];
  uint4 cur[NV], nxt[NV];
#pragma unroll
  for (int v = 0; v < NV; v++)
    cur[v] = *(const uint4*)(xl + (size_t)scur * F + ch0 + v * 8);

  for (int j = jb; j < je; j += 4) {
    // prefetch next edge's row + next-next src index
#pragma unroll
    for (int v = 0; v < NV; v++)
      nxt[v] = *(const uint4*)(xl + (size_t)snxt * F + ch0 + v * 8);
    int jnn = j + 8 + q;
    snxt = ssrc[jnn < je ? jnn : je - 1];

    f32x2 xl2[NP];
    f32x2 s2; s2.x = 0.f; s2.y = 0.f;
#pragma unroll
    for (int v = 0; v < NV; v++) {
      unsigned int dw[4] = {cur[v].x, cur[v].y, cur[v].z, cur[v].w};
#pragma unroll
      for (int k = 0; k < 4; k++) {
        const int p = v * 4 + k;
        f32x2 xv = bf2x(dw[k]);
        f32x2 m  = pk_add(xv, xr2[p]);
        f32x2 am = pk_abs(m);
        s2 = pk_fma(a06[p], m, s2);
        s2 = pk_fma(a04[p], am, s2);
        xl2[p] = xv;
      }
    }

    float s = s2.x + s2.y;
    // score reduce on the VALU pipe (DPP), no LDS-pipe waits:
    s = dppadd<0xB1>(s);        // xor 1 (quad_perm)
    s = dppadd<0x4E>(s);        // xor 2 (quad_perm)
    s = dppadd<0x141>(s);       // cross-quad within 8 (row_half_mirror)
    if (CPL == 8) s = dppadd<0x140>(s);  // cross-8 within 16 (row_mirror)
    // CPL==16: lanes 0-7 hold head-0 score, lanes 8-15 head-1 score.

    float pe = (j + q < je) ? __expf(fminf(s, 80.f)) : 0.f;
    l_run += pe;
    f32x2 p2; p2.x = pe; p2.y = pe;
#pragma unroll
    for (int p = 0; p < NP; p++) acc2[p] = pk_fma(p2, xl2[p], acc2[p]);

#pragma unroll
    for (int v = 0; v < NV; v++) cur[v] = nxt[v];
  }

  // combine the 4 edge slots (once per node)
#pragma unroll
  for (int p = 0; p < NP; p++) {
    acc2[p].x += __shfl_xor(acc2[p].x, 16, 64);
    acc2[p].x += __shfl_xor(acc2[p].x, 32, 64);
    acc2[p].y += __shfl_xor(acc2[p].y, 16, 64);
    acc2[p].y += __shfl_xor(acc2[p].y, 32, 64);
  }
  l_run += __shfl_xor(l_run, 16, 64);
  l_run += __shfl_xor(l_run, 32, 64);

  if (q == 0) {
    float inv = 1.f / (l_run + 1e-16f);
    const unsigned int* bu = (const unsigned int*)(bias + ch0);
    if (MODE == 0) {
#pragma unroll
      for (int v = 0; v < NV; v++) {
        short8 o;
#pragma unroll
        for (int k = 0; k < 4; k++) {
          const int p = v * 4 + k;
          f32x2 b = bf2x(bu[p]);
          float t0 = acc2[p].x * inv + b.x;
          float t1 = acc2[p].y * inv + b.y;
          t0 = t0 > 0.f ? t0 : (__expf(t0) - 1.f);        // elu
          t1 = t1 > 0.f ? t1 : (__expf(t1) - 1.f);
          o[k * 2]     = (short)f2bf(t0);
          o[k * 2 + 1] = (short)f2bf(t1);
        }
        *(short8*)((u16*)outv + (size_t)node * F + ch0 + v * 8) = o;
      }
    } else {
#pragma unroll
      for (int v = 0; v < NV; v++) {
        float w[8];
#pragma unroll
        for (int k = 0; k < 4; k++) {
          const int p = v * 4 + k;
          f32x2 b = bf2x(bu[p]);
          w[k * 2]     = acc2[p].x * inv + b.x;
          w[k * 2 + 1] = acc2[p].y * inv + b.y;
        }
        float* op = (float*)outv + (size_t)node * F + ch0 + v * 8;
        *(float4*)op = make_float4(w[0], w[1], w[2], w[3]);
        *(float4*)(op + 4) = make_float4(w[4], w[5], w[6], w[7]);
      }
    }
  }
}

// ---------------- BN stats (vectorized) + fold into transposed gemm2 weights ----------------
// block: 8 row-lanes x 32 ch-lanes; thread accumulates 8 channels via short8.
__global__ __launch_bounds__(256) void k_stats(
    const u16* __restrict__ h, float* __restrict__ gsum,
    float* __restrict__ gsumsq, int n) {
  __shared__ float smS[8][256], smQ[8][256];
  int t = threadIdx.x;
  int rg = t >> 5, cl = t & 31;
  int ch0 = cl * 8;
  float s[8] = {}, q[8] = {};
  for (int r = blockIdx.x * 8 + rg; r < n; r += gridDim.x * 8) {
    float v[8];
    load8(h + (size_t)r * F1 + ch0, v);
#pragma unroll
    for (int k = 0; k < 8; k++) { s[k] += v[k]; q[k] += v[k] * v[k]; }
  }
#pragma unroll
  for (int k = 0; k < 8; k++) { smS[rg][ch0 + k] = s[k]; smQ[rg][ch0 + k] = q[k]; }
  __syncthreads();
  float ts = 0.f, tq = 0.f;
#pragma unroll
  for (int g = 0; g < 8; g++) { ts += smS[g][t]; tq += smQ[g][t]; }
  atomicAdd(&gsum[t], ts);
  atomicAdd(&gsumsq[t], tq);
}

__global__ __launch_bounds__(256) void k_foldbn(
    const float* __restrict__ gsum, const float* __restrict__ gsumsq,
    const u16* __restrict__ gamma, const u16* __restrict__ beta,
    u16* __restrict__ Wl2t, u16* __restrict__ Wr2t,
    float* __restrict__ rbias, float invn) {
  __shared__ float red[8];
  int t = threadIdx.x, n = blockIdx.x;   // 128 blocks x 256 threads
  float mu = gsum[t] * invn;
  float var = gsumsq[t] * invn - mu * mu;
  float a = bf2f(gamma[t]) * rsqrtf(fmaxf(var, 0.f) + 1e-5f);
  float b = bf2f(beta[t]) - mu * a;
  float wl = bf2f(Wl2t[n * 256 + t]);
  float wr = bf2f(Wr2t[n * 256 + t]);
  float sl = b * wl, sr = b * wr;
  Wl2t[n * 256 + t] = f2bf(a * wl);
  Wr2t[n * 256 + t] = f2bf(a * wr);
#pragma unroll
  for (int m = 1; m <= 32; m <<= 1) {
    sl += __shfl_xor(sl, m, 64);
    sr += __shfl_xor(sr, m, 64);
  }
  int wave = t >> 6, lane = t & 63;
  if (lane == 0) { red[wave] = sl; red[4 + wave] = sr; }
  __syncthreads();
  if (t == 0) rbias[n] = red[0] + red[1] + red[2] + red[3];
  if (t == 1) rbias[128 + n] = red[4] + red[5] + red[6] + red[7];
}

// ---------------- pool + final linear: 1 block/graph, binary-search bounds ----------------
__device__ __forceinline__ int lowerb(const int* __restrict__ a, int n, int key) {
  int lo = 0, hi = n;
  while (lo < hi) { int m = (lo + hi) >> 1; if (a[m] < key) lo = m + 1; else hi = m; }
  return lo;
}

__global__ __launch_bounds__(256) void k_poolfinal(
    const float* __restrict__ h2, const int* __restrict__ batch,
    const u16* __restrict__ Wlin, const u16* __restrict__ blin,
    void* __restrict__ out, const int* __restrict__ flag, int G, int N) {
  __shared__ float sm[4][128];
  int g = blockIdx.x;
  int wave = threadIdx.x >> 6, lane = threadIdx.x & 63;
  int jb = lowerb(batch, N, g);
  int je = lowerb(batch, N, g + 1);
  int ch = lane * 2;
  float c0 = 0.f, c1 = 0.f;
  for (int r = jb + wave; r < je; r += 4) {
    float2 v = *(const float2*)(h2 + (size_t)r * F2 + ch);
    c0 += v.x; c1 += v.y;
  }
  sm[wave][ch] = c0;
  sm[wave][ch + 1] = c1;
  __syncthreads();
  if (wave == 0) {
    c0 = sm[0][ch] + sm[1][ch] + sm[2][ch] + sm[3][ch];
    c1 = sm[0][ch + 1] + sm[1][ch + 1] + sm[2][ch + 1] + sm[3][ch + 1];
    float cf = fmaxf((float)(je - jb), 1.f);
    c0 /= cf; c1 /= cf;
    float s0 = c0 * bf2f(Wlin[ch * 2 + 0]) + c1 * bf2f(Wlin[(ch + 1) * 2 + 0]);
    float s1 = c0 * bf2f(Wlin[ch * 2 + 1]) + c1 * bf2f(Wlin[(ch + 1) * 2 + 1]);
#pragma unroll
    for (int m = 1; m <= 32; m <<= 1) {
      s0 += __shfl_xor(s0, m, 64);
      s1 += __shfl_xor(s1, m, 64);
    }
    if (lane == 0) {
      float o0 = s0 + bf2f(blin[0]);
      float o1 = s1 + bf2f(blin[1]);
      if (*flag) {
        ((float*)out)[g * 2 + 0] = o0;
        ((float*)out)[g * 2 + 1] = o1;
      } else {
        ((u16*)out)[g * 2 + 0] = f2bf(o0);
        ((u16*)out)[g * 2 + 1] = f2bf(o1);
      }
    }
  }
}

// ---------------- host ----------------
extern "C" void kernel_launch(void* const* d_in, const int* in_sizes, int n_in,
                              void* d_out, int out_size, void* d_ws, size_t ws_size,
                              hipStream_t stream) {
  const int* ei    = (const int*)d_in[1];
  const int* batch = (const int*)d_in[2];

  const int N = in_sizes[0] / DIN;
  const int E = in_sizes[1] / 2;
  const int G = out_size / 2;
  const int Etot = E + N;

  char* p = (char*)d_ws;
  auto alloc = [&](size_t bytes) {
    char* r = p;
    p += (bytes + 255) & ~(size_t)255;
    return r;
  };
  int*  flag     = (int*)alloc(256);
  // ---- zero region (zeroed by convert_all): hist | gsum | gsumsq | pstate | ctr ----
  int*  hist     = (int*)alloc((size_t)N * 4);
  float* gsum    = (float*)alloc(1024);
  float* gsumsq  = (float*)alloc(1024);
  unsigned long long* pstate = (unsigned long long*)alloc(2048);
  int*  ctr      = (int*)alloc(256);
  int   zn       = (int)(((char*)ctr + 256) - (char*)hist) / 4;
  // ---- rest ----
  int*  rowptr   = (int*)alloc((size_t)(N + 1) * 4);
  int*  cursor   = (int*)alloc((size_t)N * 4);
  float* rbias   = (float*)alloc(256 * 4);
  int*  ssrc     = (int*)alloc((size_t)Etot * 4);
  u16*  xb       = (u16*)alloc((size_t)N * DIN * 2);
  u16*  pb       = (u16*)alloc(4096);
  u16*  Wl1t     = (u16*)alloc(DIN * F1 * 2);   // [256][128]
  u16*  Wr1t     = (u16*)alloc(DIN * F1 * 2);
  u16*  Wl2t     = (u16*)alloc(F1 * F2 * 2);    // [128][256]
  u16*  Wr2t     = (u16*)alloc(F1 * F2 * 2);
  u16*  regionA  = (u16*)alloc((size_t)N * F1 * 2);
  u16*  regionB  = (u16*)alloc((size_t)N * F1 * 2);
  u16*  regionC  = (u16*)alloc((size_t)N * F1 * 2);

  u16*  xl1  = regionA;
  u16*  xr1  = regionB;
  u16*  helu = regionC;                 // bf16 [N,F1] (gemm2 reads directly)
  u16*  xl2  = regionB;                 // bf16 [N,F2]  (B free after agg1)
  u16*  xr2  = regionB + (size_t)N * F2;
  float* h2  = (float*)regionA;         // fp32 [N,F2]  (A free after gemm2)

  // ---- fused convert (+transpose, +zero, +self-detect) ----
  const int pidx[8] = {5, 6, 7, 8, 11, 12, 13, 14};  // att1,b1,gamma,beta,att2,b2,Wlin,blin
  PTab tab;
  int accum = 0;
  for (int i = 0; i < 8; i++) {
    tab.src[i] = d_in[pidx[i]];
    tab.off[i] = accum;
    accum += in_sizes[pidx[i]];
  }
  tab.off[8] = accum;
  int n4 = in_sizes[0] / 4;
  int nxb = (n4 + 255) / 256;
  int npb = (accum + 255) / 256;
  int nzb = (zn + 255) / 256;
  k_convert_all<<<nxb + npb + 512 + nzb, 256, 0, stream>>>(
      d_in[0], xb, n4, nxb, tab, pb, accum, npb,
      d_in[3], d_in[4], d_in[9], d_in[10], Wl1t, Wr1t, Wl2t, Wr2t,
      hist, zn, flag);
  u16 *pAtt1 = pb + tab.off[0], *pB1 = pb + tab.off[1], *pGamma = pb + tab.off[2],
      *pBeta = pb + tab.off[3], *pAtt2 = pb + tab.off[4], *pB2 = pb + tab.off[5],
      *pWlin = pb + tab.off[6], *pBlin = pb + tab.off[7];

  const int eb = (Etot + 255) / 256;
  const int sb = (N + 255) / 256;

  k_hist<<<eb, 256, 0, stream>>>(ei, hist, E, Etot);
  k_scan<<<sb, 256, 0, stream>>>(hist, rowptr, cursor, pstate, ctr, N, Etot);
  k_scatter<<<eb, 256, 0, stream>>>(ei, cursor, ssrc, E, Etot);

  dim3 g1((N + 63) / 64, (2 * F1) / 64);
  k_gemm<DIN, false><<<g1, 256, 0, stream>>>(xb, Wl1t, Wr1t, F1, xl1, xr1, N, nullptr);

  k_agg<16, 0><<<(N + 3) / 4, 256, 0, stream>>>(xl1, xr1, pAtt1, pB1, rowptr, ssrc, helu, N);

  k_stats<<<256, 256, 0, stream>>>(helu, gsum, gsumsq, N);
  k_foldbn<<<128, 256, 0, stream>>>(gsum, gsumsq, pGamma, pBeta, Wl2t, Wr2t, rbias,
                                    1.0f / (float)N);

  dim3 g2((N + 63) / 64, (2 * F2) / 64);
  k_gemm<F1, true><<<g2, 256, 0, stream>>>(helu, Wl2t, Wr2t, F2, xl2, xr2, N, rbias);

  k_agg<8, 1><<<(N + 3) / 4, 256, 0, stream>>>(xl2, xr2, pAtt2, pB2, rowptr, ssrc, h2, N);

  k_poolfinal<<<G, 256, 0, stream>>>(h2, batch, pWlin, pBlin, d_out, flag, G, N);
}

// Round 3
// 434.620 us; speedup vs baseline: 1.0560x; 1.0323x over previous
//
#include <hip/hip_runtime.h>

// GATv2 2-layer GNN, MI355X. Inputs/out fp32 (proven r3); compute bf16.
// Round-13: k_agg latency cover. r12 showed VALUBusy 69% (31% latency gaps):
// 2-deep pipeline gave only ~1 slot lookahead and 8 v_movs/slot rotation;
// ssrc loaded in the consuming iteration. This round:
// (1) ping-pong bufA/bufB, loop unrolled 2 slots -> no rotation movs, refill
//     issued a full iteration before use;
// (2) ssrc index prefetch 2 iterations ahead (sA2/sB2);
// (3) tail-exact loop (j+4<je step 8, trailing single A-slot) keeps masked-
//     position waste at r12 level;
// (4) att*leaky(m) = a06*(m + (2/3)|m|), a06=0.6att -> a04 array deleted
//     (-16 VGPR), same per-pair op count.
// Rest of pipeline unchanged (r9-r12 proven).

#define DIN 128
#define F1 256   // H*DH layer 1
#define F2 128   // DOUT
#define NEG_SLOPE 0.2f

typedef unsigned short u16;
typedef __attribute__((ext_vector_type(8))) short short8;
typedef __attribute__((ext_vector_type(4))) float floatx4;
typedef __attribute__((ext_vector_type(2))) float f32x2;

__device__ __forceinline__ float bf2f(u16 u) {
  return __uint_as_float(((unsigned int)u) << 16);
}
__device__ __forceinline__ u16 f2bf(float f) {   // round-to-nearest-even
  unsigned int x = __float_as_uint(f);
  return (u16)((x + 0x7fffu + ((x >> 16) & 1u)) >> 16);
}
__device__ __forceinline__ void load8(const u16* p, float (&f)[8]) {
  short8 v = *(const short8*)p;
#pragma unroll
  for (int k = 0; k < 8; k++) f[k] = bf2f((u16)v[k]);
}

// expand one dword holding 2 bf16 (little-endian: lo ch = low u16)
__device__ __forceinline__ f32x2 bf2x(unsigned int u) {
  f32x2 r;
  r.x = __uint_as_float(u << 16);
  r.y = __uint_as_float(u & 0xffff0000u);
  return r;
}
// packed fp32 (VOP3P, full-rate on CDNA): 2 f32 lanes per instruction
__device__ __forceinline__ f32x2 pk_add(f32x2 a, f32x2 b) {
  f32x2 d;
  asm("v_pk_add_f32 %0, %1, %2" : "=v"(d) : "v"(a), "v"(b));
  return d;
}
__device__ __forceinline__ f32x2 pk_fma(f32x2 a, f32x2 b, f32x2 c) {
  f32x2 d;
  asm("v_pk_fma_f32 %0, %1, %2, %3" : "=v"(d) : "v"(a), "v"(b), "v"(c));
  return d;
}
__device__ __forceinline__ f32x2 pk_abs(f32x2 a) {
  f32x2 r;
  r.x = __uint_as_float(__float_as_uint(a.x) & 0x7fffffffu);
  r.y = __uint_as_float(__float_as_uint(a.y) & 0x7fffffffu);
  return r;
}

// DPP-based add of lane (self ^ pattern); VALU pipe only.
// 0xB1 = quad_perm xor1, 0x4E = quad_perm xor2, 0x141 = row_half_mirror
// (crosses quads within 8), 0x140 = row_mirror (crosses 8-groups within 16).
template <int CTRL>
__device__ __forceinline__ float dppadd(float s) {
  int t = __builtin_amdgcn_update_dpp(0, __float_as_int(s), CTRL, 0xF, 0xF, false);
  return s + __int_as_float(t);
}

// ---------------- fused convert + transpose + zero + self-detect ----------------
struct PTab { const void* src[8]; int off[9]; };
__global__ __launch_bounds__(256) void k_convert_all(
    const void* __restrict__ xsrc, u16* __restrict__ xb, int n4, int nxb,
    PTab t, u16* __restrict__ pb, int ptotal, int npb,
    const void* __restrict__ Wl1s, const void* __restrict__ Wr1s,
    const void* __restrict__ Wl2s, const void* __restrict__ Wr2s,
    u16* __restrict__ Wl1t, u16* __restrict__ Wr1t,
    u16* __restrict__ Wl2t, u16* __restrict__ Wr2t,
    int* __restrict__ zbase, int zn, int* __restrict__ flag) {
  __shared__ int flagS;
  int tid = threadIdx.x;
  if (tid < 64) {
    int cnt = 0;
#pragma unroll
    for (int i = 0; i < 2; ++i) {
      u16 v = ((const u16*)xsrc)[2 * (tid + 64 * i)];  // even u16: fp32 low halves
      int e = (v >> 7) & 0xFF;
      if (e >= 115 && e <= 130) cnt++;                 // bf16 N(0,1) exponent range
    }
#pragma unroll
    for (int m = 1; m <= 32; m <<= 1) cnt += __shfl_xor(cnt, m, 64);
    if (tid == 0) flagS = (cnt < 64) ? 1 : 0;
  }
  __syncthreads();
  const int fl = flagS;
  if (blockIdx.x == 0 && tid == 0) *flag = fl;   // persist for poolfinal

  int b = blockIdx.x;
  if (b < nxb) {                                  // x convert, 4 elems/thread
    int i = b * 256 + tid;
    if (i >= n4) return;
    if (fl) {
      float4 a = ((const float4*)xsrc)[i];
      ushort4 o;
      o.x = f2bf(a.x); o.y = f2bf(a.y); o.z = f2bf(a.z); o.w = f2bf(a.w);
      ((ushort4*)xb)[i] = o;
    } else {
      ((ulong1*)xb)[i] = ((const ulong1*)xsrc)[i];
    }
    return;
  }
  b -= nxb;
  if (b < npb) {                                  // small params (no W's)
    int i = b * 256 + tid;
    if (i >= ptotal) return;
    int s = 0;
#pragma unroll
    for (int k = 1; k < 8; k++) s += (i >= t.off[k]);
    int local = i - t.off[s];
    pb[i] = fl ? f2bf(((const float*)t.src[s])[local]) : ((const u16*)t.src[s])[local];
    return;
  }
  b -= npb;
  if (b < 512) {
    // weight transposes: W[K,NL] -> Wt[NL,K]; 4 segs x 128 blocks
    int seg = b >> 7;
    int i = (b & 127) * 256 + tid;
    const void* s; u16* d; int NL, sh;
    if      (seg == 0) { s = Wl1s; d = Wl1t; NL = 256; sh = 7; }
    else if (seg == 1) { s = Wr1s; d = Wr1t; NL = 256; sh = 7; }
    else if (seg == 2) { s = Wl2s; d = Wl2t; NL = 128; sh = 8; }
    else               { s = Wr2s; d = Wr2t; NL = 128; sh = 8; }
    int n = i >> sh, k = i & ((1 << sh) - 1);
    int si = k * NL + n;
    d[i] = fl ? f2bf(((const float*)s)[si]) : ((const u16*)s)[si];
    return;
  }
  b -= 512;
  int i = b * 256 + tid;                          // zero region (ints)
  if (i < zn) zbase[i] = 0;
}

// ---------------- CSR build ----------------
__global__ void k_hist(const int* __restrict__ ei, int* __restrict__ hist,
                       int E, int Etot) {
  int e = blockIdx.x * 256 + threadIdx.x;
  if (e >= Etot) return;
  int dst = (e < E) ? ei[E + e] : (e - E);
  atomicAdd(&hist[dst], 1);
}

// single-pass decoupled-lookback exclusive scan; writes rowptr & cursor
__global__ void k_scan(const int* __restrict__ hist, int* __restrict__ rowptr,
                       int* __restrict__ cursor, unsigned long long* __restrict__ pstate,
                       int* __restrict__ ctr, int n, int Etot) {
  __shared__ int tmp[256];
  __shared__ int bidS, offS;
  int t = threadIdx.x;
  if (t == 0) bidS = atomicAdd(ctr, 1);
  __syncthreads();
  int bid = bidS;
  int gid = bid * 256 + t;
  int v = (gid < n) ? hist[gid] : 0;
  tmp[t] = v;
  __syncthreads();
  for (int off = 1; off < 256; off <<= 1) {
    int add = (t >= off) ? tmp[t - off] : 0;
    __syncthreads();
    tmp[t] += add;
    __syncthreads();
  }
  if (t == 0) {
    int total = tmp[255];
    unsigned long long st =
        ((unsigned long long)(bid == 0 ? 2 : 1) << 32) | (unsigned)total;
    atomicExch(&pstate[bid], st);
    int off = 0;
    if (bid > 0) {
      int b = bid - 1;
      while (true) {
        unsigned long long s;
        do { s = atomicAdd(&pstate[b], 0ULL); } while ((s >> 32) == 0);
        off += (int)(unsigned)s;
        if ((s >> 32) == 2) break;
        b--;
      }
      atomicExch(&pstate[bid],
                 ((unsigned long long)2 << 32) | (unsigned)(off + total));
    }
    offS = off;
  }
  __syncthreads();
  int off = offS;
  if (gid < n) {
    int ex = off + tmp[t] - v;
    rowptr[gid] = ex;
    cursor[gid] = ex;
  }
  if (gid == 0) rowptr[n] = Etot;
}

__global__ void k_scatter(const int* __restrict__ ei, int* __restrict__ cursor,
                          int* __restrict__ ssrc, int E, int Etot) {
  int e = blockIdx.x * 256 + threadIdx.x;
  if (e >= Etot) return;
  int src, dst;
  if (e < E) { src = ei[e]; dst = ei[E + e]; }
  else       { src = e - E; dst = e - E; }
  int pos = atomicAdd(&cursor[dst], 1);
  ssrc[pos] = src;
}

// ---------------- GEMM: LDS-free, B pre-transposed Bt[NL][K] (r9-proven) ----------------
template<int K, bool RB>
__global__ __launch_bounds__(256) void k_gemm(
    const u16* __restrict__ A, const u16* __restrict__ Blt, const u16* __restrict__ Brt,
    int NL, u16* __restrict__ Cl, u16* __restrict__ Cr, int M,
    const float* __restrict__ rbias) {
  const int tid = threadIdx.x;
  const int m0 = blockIdx.x * 64;
  const int n0g = blockIdx.y * 64;
  const u16* Bt; u16* C; int col0;
  if (n0g < NL) { Bt = Blt; C = Cl; col0 = n0g; }
  else          { Bt = Brt; C = Cr; col0 = n0g - NL; }

  const int wave = tid >> 6, lane = tid & 63;
  const int wm = wave >> 1, wn = wave & 1;
  const int quad = lane >> 4, l16 = lane & 15;

  floatx4 acc[2][2] = {};
#pragma unroll
  for (int k0 = 0; k0 < K; k0 += 32) {
    short8 af[2], bfr[2];
#pragma unroll
    for (int mt = 0; mt < 2; mt++) {
      int row = m0 + wm * 32 + mt * 16 + l16;
      if (row > M - 1) row = M - 1;
      af[mt] = *(const short8*)(A + (size_t)row * K + k0 + quad * 8);
    }
#pragma unroll
    for (int nt = 0; nt < 2; nt++) {
      int nn = col0 + wn * 32 + nt * 16 + l16;
      bfr[nt] = *(const short8*)(Bt + (size_t)nn * K + k0 + quad * 8);
    }
#pragma unroll
    for (int mt = 0; mt < 2; mt++)
#pragma unroll
      for (int nt = 0; nt < 2; nt++)
        acc[mt][nt] = __builtin_amdgcn_mfma_f32_16x16x32_bf16(af[mt], bfr[nt], acc[mt][nt], 0, 0, 0);
  }

#pragma unroll
  for (int mt = 0; mt < 2; mt++)
#pragma unroll
    for (int nt = 0; nt < 2; nt++) {
      float rb = 0.f;
      if (RB) rb = rbias[n0g + wn * 32 + nt * 16 + l16];
#pragma unroll
      for (int r = 0; r < 4; r++) {
        int row = m0 + wm * 32 + mt * 16 + quad * 4 + r;
        if (row < M) {
          int col = col0 + wn * 32 + nt * 16 + l16;
          C[(size_t)row * NL + col] = f2bf(acc[mt][nt][r] + rb);
        }
      }
    }
}

// ---------------- aggregation: quarter-per-edge, packed f32, ping-pong pipeline ----------------
// CPL = channels per lane (F = 16*CPL). CPL=16: layer 1 (2 heads, head
// boundary at lane 8 -> 3-stage score reduce). CPL=8: layer 2 (1 head,
// 4-stage reduce). Each 16-lane quarter owns one edge. bufA/bufB ping-pong:
// a slot's row load is issued a full iteration before use; ssrc indices
// prefetched 2 iterations ahead. Score: att*leaky(m) = a06*(m + (2/3)|m|).
template<int CPL, int MODE>
__global__ __launch_bounds__(256) void k_agg(
    const u16* __restrict__ xl, const u16* __restrict__ xr,
    const u16* __restrict__ att, const u16* __restrict__ bias,
    const int* __restrict__ rowptr, const int* __restrict__ ssrc,
    void* __restrict__ outv, int n) {
  constexpr int F = CPL * 16;
  constexpr int NV = CPL / 8;   // uint4 (16B) loads per edge-lane
  constexpr int NP = CPL / 2;   // f32x2 pairs per lane
  int wave = threadIdx.x >> 6, lane = threadIdx.x & 63;
  int node = blockIdx.x * 4 + wave;
  if (node >= n) return;
  const int q = lane >> 4, l = lane & 15;
  const int ch0 = l * CPL;

  f32x2 xr2[NP], a06[NP], acc2[NP];
  {
    const unsigned int* xru = (const unsigned int*)(xr + (size_t)node * F + ch0);
    const unsigned int* atu = (const unsigned int*)(att + ch0);
#pragma unroll
    for (int p = 0; p < NP; p++) {
      xr2[p] = bf2x(xru[p]);
      f32x2 a = bf2x(atu[p]);
      a06[p].x = 0.6f * a.x; a06[p].y = 0.6f * a.y;
      acc2[p].x = 0.f;       acc2[p].y = 0.f;
    }
  }
  f32x2 c23; c23.x = 2.0f / 3.0f; c23.y = 2.0f / 3.0f;

  const int jb = __builtin_amdgcn_readfirstlane(rowptr[node]);
  const int je = __builtin_amdgcn_readfirstlane(rowptr[node + 1]);
  const int jec = je - 1;
  float l_run = 0.f;

  auto cidx = [&](int j) -> int { return j < jec ? j : jec; };

  uint4 bufA[NV], bufB[NV];
  auto REFILL = [&](uint4 (&buf)[NV], int srow) {
#pragma unroll
    for (int v = 0; v < NV; v++)
      buf[v] = *(const uint4*)(xl + (size_t)srow * F + ch0 + v * 8);
  };

  // slot compute: edges jbase..jbase+3 (this group's edge = jbase + q)
  auto SLOT = [&](uint4 (&buf)[NV], int jbase) {
    f32x2 xl2[NP];
    f32x2 s2; s2.x = 0.f; s2.y = 0.f;
#pragma unroll
    for (int v = 0; v < NV; v++) {
      unsigned int dw[4] = {buf[v].x, buf[v].y, buf[v].z, buf[v].w};
#pragma unroll
      for (int k = 0; k < 4; k++) {
        const int p = v * 4 + k;
        f32x2 xv = bf2x(dw[k]);
        f32x2 m  = pk_add(xv, xr2[p]);
        f32x2 am = pk_abs(m);
        f32x2 t  = pk_fma(am, c23, m);     // m + (2/3)|m|
        s2 = pk_fma(a06[p], t, s2);
        xl2[p] = xv;
      }
    }
    float s = s2.x + s2.y;
    s = dppadd<0xB1>(s);        // xor 1 (quad_perm)
    s = dppadd<0x4E>(s);        // xor 2 (quad_perm)
    s = dppadd<0x141>(s);       // cross-quad within 8 (row_half_mirror)
    if (CPL == 8) s = dppadd<0x140>(s);  // cross-8 within 16 (row_mirror)
    float pe = (jbase + q < je) ? __expf(fminf(s, 80.f)) : 0.f;
    l_run += pe;
    f32x2 p2; p2.x = pe; p2.y = pe;
#pragma unroll
    for (int p = 0; p < NP; p++) acc2[p] = pk_fma(p2, xl2[p], acc2[p]);
  };

  // prologue: fill both slots, prefetch refill indices 2 iterations out
  REFILL(bufA, ssrc[cidx(jb + q)]);
  REFILL(bufB, ssrc[cidx(jb + 4 + q)]);
  int sA2 = ssrc[cidx(jb + 8 + q)];
  int sB2 = ssrc[cidx(jb + 12 + q)];

  int j = jb;
  for (; j + 4 < je; j += 8) {
    SLOT(bufA, j);
    REFILL(bufA, sA2);          // row for slot A of next iteration (j+8)
    SLOT(bufB, j + 4);
    REFILL(bufB, sB2);          // row for slot B of next iteration (j+12)
    sA2 = ssrc[cidx(j + 16 + q)];
    sB2 = ssrc[cidx(j + 20 + q)];
  }
  if (j < je) SLOT(bufA, j);    // trailing <=4 edges

  // combine the 4 edge slots (once per node)
#pragma unroll
  for (int p = 0; p < NP; p++) {
    acc2[p].x += __shfl_xor(acc2[p].x, 16, 64);
    acc2[p].x += __shfl_xor(acc2[p].x, 32, 64);
    acc2[p].y += __shfl_xor(acc2[p].y, 16, 64);
    acc2[p].y += __shfl_xor(acc2[p].y, 32, 64);
  }
  l_run += __shfl_xor(l_run, 16, 64);
  l_run += __shfl_xor(l_run, 32, 64);

  if (q == 0) {
    float inv = 1.f / (l_run + 1e-16f);
    const unsigned int* bu = (const unsigned int*)(bias + ch0);
    if (MODE == 0) {
#pragma unroll
      for (int v = 0; v < NV; v++) {
        short8 o;
#pragma unroll
        for (int k = 0; k < 4; k++) {
          const int p = v * 4 + k;
          f32x2 b = bf2x(bu[p]);
          float t0 = acc2[p].x * inv + b.x;
          float t1 = acc2[p].y * inv + b.y;
          t0 = t0 > 0.f ? t0 : (__expf(t0) - 1.f);        // elu
          t1 = t1 > 0.f ? t1 : (__expf(t1) - 1.f);
          o[k * 2]     = (short)f2bf(t0);
          o[k * 2 + 1] = (short)f2bf(t1);
        }
        *(short8*)((u16*)outv + (size_t)node * F + ch0 + v * 8) = o;
      }
    } else {
#pragma unroll
      for (int v = 0; v < NV; v++) {
        float w[8];
#pragma unroll
        for (int k = 0; k < 4; k++) {
          const int p = v * 4 + k;
          f32x2 b = bf2x(bu[p]);
          w[k * 2]     = acc2[p].x * inv + b.x;
          w[k * 2 + 1] = acc2[p].y * inv + b.y;
        }
        float* op = (float*)outv + (size_t)node * F + ch0 + v * 8;
        *(float4*)op = make_float4(w[0], w[1], w[2], w[3]);
        *(float4*)(op + 4) = make_float4(w[4], w[5], w[6], w[7]);
      }
    }
  }
}

// ---------------- BN stats (vectorized) + fold into transposed gemm2 weights ----------------
// block: 8 row-lanes x 32 ch-lanes; thread accumulates 8 channels via short8.
__global__ __launch_bounds__(256) void k_stats(
    const u16* __restrict__ h, float* __restrict__ gsum,
    float* __restrict__ gsumsq, int n) {
  __shared__ float smS[8][256], smQ[8][256];
  int t = threadIdx.x;
  int rg = t >> 5, cl = t & 31;
  int ch0 = cl * 8;
  float s[8] = {}, q[8] = {};
  for (int r = blockIdx.x * 8 + rg; r < n; r += gridDim.x * 8) {
    float v[8];
    load8(h + (size_t)r * F1 + ch0, v);
#pragma unroll
    for (int k = 0; k < 8; k++) { s[k] += v[k]; q[k] += v[k] * v[k]; }
  }
#pragma unroll
  for (int k = 0; k < 8; k++) { smS[rg][ch0 + k] = s[k]; smQ[rg][ch0 + k] = q[k]; }
  __syncthreads();
  float ts = 0.f, tq = 0.f;
#pragma unroll
  for (int g = 0; g < 8; g++) { ts += smS[g][t]; tq += smQ[g][t]; }
  atomicAdd(&gsum[t], ts);
  atomicAdd(&gsumsq[t], tq);
}

__global__ __launch_bounds__(256) void k_foldbn(
    const float* __restrict__ gsum, const float* __restrict__ gsumsq,
    const u16* __restrict__ gamma, const u16* __restrict__ beta,
    u16* __restrict__ Wl2t, u16* __restrict__ Wr2t,
    float* __restrict__ rbias, float invn) {
  __shared__ float red[8];
  int t = threadIdx.x, n = blockIdx.x;   // 128 blocks x 256 threads
  float mu = gsum[t] * invn;
  float var = gsumsq[t] * invn - mu * mu;
  float a = bf2f(gamma[t]) * rsqrtf(fmaxf(var, 0.f) + 1e-5f);
  float b = bf2f(beta[t]) - mu * a;
  float wl = bf2f(Wl2t[n * 256 + t]);
  float wr = bf2f(Wr2t[n * 256 + t]);
  float sl = b * wl, sr = b * wr;
  Wl2t[n * 256 + t] = f2bf(a * wl);
  Wr2t[n * 256 + t] = f2bf(a * wr);
#pragma unroll
  for (int m = 1; m <= 32; m <<= 1) {
    sl += __shfl_xor(sl, m, 64);
    sr += __shfl_xor(sr, m, 64);
  }
  int wave = t >> 6, lane = t & 63;
  if (lane == 0) { red[wave] = sl; red[4 + wave] = sr; }
  __syncthreads();
  if (t == 0) rbias[n] = red[0] + red[1] + red[2] + red[3];
  if (t == 1) rbias[128 + n] = red[4] + red[5] + red[6] + red[7];
}

// ---------------- pool + final linear: 1 block/graph, binary-search bounds ----------------
__device__ __forceinline__ int lowerb(const int* __restrict__ a, int n, int key) {
  int lo = 0, hi = n;
  while (lo < hi) { int m = (lo + hi) >> 1; if (a[m] < key) lo = m + 1; else hi = m; }
  return lo;
}

__global__ __launch_bounds__(256) void k_poolfinal(
    const float* __restrict__ h2, const int* __restrict__ batch,
    const u16* __restrict__ Wlin, const u16* __restrict__ blin,
    void* __restrict__ out, const int* __restrict__ flag, int G, int N) {
  __shared__ float sm[4][128];
  int g = blockIdx.x;
  int wave = threadIdx.x >> 6, lane = threadIdx.x & 63;
  int jb = lowerb(batch, N, g);
  int je = lowerb(batch, N, g + 1);
  int ch = lane * 2;
  float c0 = 0.f, c1 = 0.f;
  for (int r = jb + wave; r < je; r += 4) {
    float2 v = *(const float2*)(h2 + (size_t)r * F2 + ch);
    c0 += v.x; c1 += v.y;
  }
  sm[wave][ch] = c0;
  sm[wave][ch + 1] = c1;
  __syncthreads();
  if (wave == 0) {
    c0 = sm[0][ch] + sm[1][ch] + sm[2][ch] + sm[3][ch];
    c1 = sm[0][ch + 1] + sm[1][ch + 1] + sm[2][ch + 1] + sm[3][ch + 1];
    float cf = fmaxf((float)(je - jb), 1.f);
    c0 /= cf; c1 /= cf;
    float s0 = c0 * bf2f(Wlin[ch * 2 + 0]) + c1 * bf2f(Wlin[(ch + 1) * 2 + 0]);
    float s1 = c0 * bf2f(Wlin[ch * 2 + 1]) + c1 * bf2f(Wlin[(ch + 1) * 2 + 1]);
#pragma unroll
    for (int m = 1; m <= 32; m <<= 1) {
      s0 += __shfl_xor(s0, m, 64);
      s1 += __shfl_xor(s1, m, 64);
    }
    if (lane == 0) {
      float o0 = s0 + bf2f(blin[0]);
      float o1 = s1 + bf2f(blin[1]);
      if (*flag) {
        ((float*)out)[g * 2 + 0] = o0;
        ((float*)out)[g * 2 + 1] = o1;
      } else {
        ((u16*)out)[g * 2 + 0] = f2bf(o0);
        ((u16*)out)[g * 2 + 1] = f2bf(o1);
      }
    }
  }
}

// ---------------- host ----------------
extern "C" void kernel_launch(void* const* d_in, const int* in_sizes, int n_in,
                              void* d_out, int out_size, void* d_ws, size_t ws_size,
                              hipStream_t stream) {
  const int* ei    = (const int*)d_in[1];
  const int* batch = (const int*)d_in[2];

  const int N = in_sizes[0] / DIN;
  const int E = in_sizes[1] / 2;
  const int G = out_size / 2;
  const int Etot = E + N;

  char* p = (char*)d_ws;
  auto alloc = [&](size_t bytes) {
    char* r = p;
    p += (bytes + 255) & ~(size_t)255;
    return r;
  };
  int*  flag     = (int*)alloc(256);
  // ---- zero region (zeroed by convert_all): hist | gsum | gsumsq | pstate | ctr ----
  int*  hist     = (int*)alloc((size_t)N * 4);
  float* gsum    = (float*)alloc(1024);
  float* gsumsq  = (float*)alloc(1024);
  unsigned long long* pstate = (unsigned long long*)alloc(2048);
  int*  ctr      = (int*)alloc(256);
  int   zn       = (int)(((char*)ctr + 256) - (char*)hist) / 4;
  // ---- rest ----
  int*  rowptr   = (int*)alloc((size_t)(N + 1) * 4);
  int*  cursor   = (int*)alloc((size_t)N * 4);
  float* rbias   = (float*)alloc(256 * 4);
  int*  ssrc     = (int*)alloc((size_t)Etot * 4);
  u16*  xb       = (u16*)alloc((size_t)N * DIN * 2);
  u16*  pb       = (u16*)alloc(4096);
  u16*  Wl1t     = (u16*)alloc(DIN * F1 * 2);   // [256][128]
  u16*  Wr1t     = (u16*)alloc(DIN * F1 * 2);
  u16*  Wl2t     = (u16*)alloc(F1 * F2 * 2);    // [128][256]
  u16*  Wr2t     = (u16*)alloc(F1 * F2 * 2);
  u16*  regionA  = (u16*)alloc((size_t)N * F1 * 2);
  u16*  regionB  = (u16*)alloc((size_t)N * F1 * 2);
  u16*  regionC  = (u16*)alloc((size_t)N * F1 * 2);

  u16*  xl1  = regionA;
  u16*  xr1  = regionB;
  u16*  helu = regionC;                 // bf16 [N,F1] (gemm2 reads directly)
  u16*  xl2  = regionB;                 // bf16 [N,F2]  (B free after agg1)
  u16*  xr2  = regionB + (size_t)N * F2;
  float* h2  = (float*)regionA;         // fp32 [N,F2]  (A free after gemm2)

  // ---- fused convert (+transpose, +zero, +self-detect) ----
  const int pidx[8] = {5, 6, 7, 8, 11, 12, 13, 14};  // att1,b1,gamma,beta,att2,b2,Wlin,blin
  PTab tab;
  int accum = 0;
  for (int i = 0; i < 8; i++) {
    tab.src[i] = d_in[pidx[i]];
    tab.off[i] = accum;
    accum += in_sizes[pidx[i]];
  }
  tab.off[8] = accum;
  int n4 = in_sizes[0] / 4;
  int nxb = (n4 + 255) / 256;
  int npb = (accum + 255) / 256;
  int nzb = (zn + 255) / 256;
  k_convert_all<<<nxb + npb + 512 + nzb, 256, 0, stream>>>(
      d_in[0], xb, n4, nxb, tab, pb, accum, npb,
      d_in[3], d_in[4], d_in[9], d_in[10], Wl1t, Wr1t, Wl2t, Wr2t,
      hist, zn, flag);
  u16 *pAtt1 = pb + tab.off[0], *pB1 = pb + tab.off[1], *pGamma = pb + tab.off[2],
      *pBeta = pb + tab.off[3], *pAtt2 = pb + tab.off[4], *pB2 = pb + tab.off[5],
      *pWlin = pb + tab.off[6], *pBlin = pb + tab.off[7];

  const int eb = (Etot + 255) / 256;
  const int sb = (N + 255) / 256;

  k_hist<<<eb, 256, 0, stream>>>(ei, hist, E, Etot);
  k_scan<<<sb, 256, 0, stream>>>(hist, rowptr, cursor, pstate, ctr, N, Etot);
  k_scatter<<<eb, 256, 0, stream>>>(ei, cursor, ssrc, E, Etot);

  dim3 g1((N + 63) / 64, (2 * F1) / 64);
  k_gemm<DIN, false><<<g1, 256, 0, stream>>>(xb, Wl1t, Wr1t, F1, xl1, xr1, N, nullptr);

  k_agg<16, 0><<<(N + 3) / 4, 256, 0, stream>>>(xl1, xr1, pAtt1, pB1, rowptr, ssrc, helu, N);

  k_stats<<<256, 256, 0, stream>>>(helu, gsum, gsumsq, N);
  k_foldbn<<<128, 256, 0, stream>>>(gsum, gsumsq, pGamma, pBeta, Wl2t, Wr2t, rbias,
                                    1.0f / (float)N);

  dim3 g2((N + 63) / 64, (2 * F2) / 64);
  k_gemm<F1, true><<<g2, 256, 0, stream>>>(helu, Wl2t, Wr2t, F2, xl2, xr2, N, rbias);

  k_agg<8, 1><<<(N + 3) / 4, 256, 0, stream>>>(xl2, xr2, pAtt2, pB2, rowptr, ssrc, h2, N);

  k_poolfinal<<<G, 256, 0, stream>>>(h2, batch, pWlin, pBlin, d_out, flag, G, N);
}